// Round 1
// baseline (282.745 us; speedup 1.0000x reference)
//
#include <hip/hip_runtime.h>

static constexpr int BLOCK = 256;
static constexpr int SPT   = 4;              // samples per thread
static constexpr int SPB   = BLOCK * SPT;    // 1024 samples per block
static constexpr int F4PB  = SPB * 3 / 4;    // 768 float4s per array per block

__device__ __forceinline__ float sample_contrib(float l0, float l1, float l2,
                                                float t0, float t1, float t2,
                                                float c, int lab) {
    // adaptive temperature
    float temp;
    if (c > 0.9f)      temp = 1.5f;
    else if (c > 0.6f) temp = 2.0f;
    else               temp = fminf(2.5f + (0.6f - c) * 2.0f, 3.0f);
    float invT = 1.0f / temp;

    // log_softmax(logits / T); sum(t) == 1 so KL = sum t*log t - sum t*a + lse
    float a0 = l0 * invT, a1 = l1 * invT, a2 = l2 * invT;
    float m  = fmaxf(a0, fmaxf(a1, a2));
    float s  = __expf(a0 - m) + __expf(a1 - m) + __expf(a2 - m);
    float lse = __logf(s) + m;

    float tlogt = t0 * __logf(t0) + t1 * __logf(t1) + t2 * __logf(t2);
    float ta    = t0 * a0 + t1 * a1 + t2 * a2;
    float kl    = tlogt - ta + lse;

    // CE with unscaled logits
    float m2 = fmaxf(l0, fmaxf(l1, l2));
    float s2 = __expf(l0 - m2) + __expf(l1 - m2) + __expf(l2 - m2);
    float lse2 = __logf(s2) + m2;
    float ll = (lab == 0) ? l0 : ((lab == 1) ? l1 : l2);
    float ce = lse2 - ll;

    return 0.5f * kl + 0.5f * ce;
}

__global__ __launch_bounds__(BLOCK) void adl_main(
    const float4* __restrict__ l4,
    const int*    __restrict__ hard,
    const float4* __restrict__ s4,
    const float*  __restrict__ conf,
    double*       __restrict__ ws_sum,
    int B)
{
    // Coalescing fix: stage logits/soft via LDS so every global VMEM instr is
    // lane-contiguous (16 B/lane, 8 lines/instr instead of 48 at the old 96 B
    // per-lane stride). Sample->thread assignment is arbitrary (output is a
    // sum), so thread t takes samples {t, t+256, t+512, t+768}: LDS word addr
    // 3t+const, gcd(3,32)=1 -> exactly 2 lanes/bank = conflict-free.
    __shared__ float ldsL[SPB * 3];   // 12288 B
    __shared__ float ldsS[SPB * 3];   // 12288 B

    const int t = threadIdx.x;
    const long long base = (long long)blockIdx.x * SPB;
    float part = 0.0f;

    if (base + SPB <= (long long)B) {
        const float4* gl = l4 + (size_t)blockIdx.x * F4PB;
        const float4* gs = s4 + (size_t)blockIdx.x * F4PB;
        // global -> LDS direct (async, no VGPR round-trip); dest is linear:
        // wave-uniform base + lane*16, exactly the HW constraint.
#pragma unroll
        for (int k = 0; k < 3; ++k)
            __builtin_amdgcn_global_load_lds(
                (const __attribute__((address_space(1))) void*)(gl + k * BLOCK + t),
                (__attribute__((address_space(3))) void*)(&ldsL[(k * BLOCK + t) * 4]),
                16, 0, 0);
#pragma unroll
        for (int k = 0; k < 3; ++k)
            __builtin_amdgcn_global_load_lds(
                (const __attribute__((address_space(1))) void*)(gs + k * BLOCK + t),
                (__attribute__((address_space(3))) void*)(&ldsS[(k * BLOCK + t) * 4]),
                16, 0, 0);

        // conf/labels: unit-stride dword loads under the remapped assignment.
        float cf[SPT];
        int   lb[SPT];
#pragma unroll
        for (int j = 0; j < SPT; ++j) {
            cf[j] = conf[base + j * BLOCK + t];
            lb[j] = hard[base + j * BLOCK + t];
        }
        __syncthreads();   // drains vmcnt (incl. global_load_lds) before reads

#pragma unroll
        for (int j = 0; j < SPT; ++j) {
            int s = j * BLOCK + t;
            part += sample_contrib(ldsL[3 * s], ldsL[3 * s + 1], ldsL[3 * s + 2],
                                   ldsS[3 * s], ldsS[3 * s + 1], ldsS[3 * s + 2],
                                   cf[j], lb[j]);
        }
    } else {
        // tail path (not taken for B = 8388608 = 8192 * 1024); block-uniform branch
        const float* lf = (const float*)l4;
        const float* sf = (const float*)s4;
        for (int j = 0; j < SPT; ++j) {
            long long s = base + (long long)j * BLOCK + t;
            if (s < (long long)B)
                part += sample_contrib(lf[3 * s], lf[3 * s + 1], lf[3 * s + 2],
                                       sf[3 * s], sf[3 * s + 1], sf[3 * s + 2],
                                       conf[s], hard[s]);
        }
    }

    // block reduction -> one double atomic
    double acc = (double)part;
#pragma unroll
    for (int off = 32; off > 0; off >>= 1)
        acc += __shfl_down(acc, off, 64);

    __shared__ double red[BLOCK / 64];
    int lane = t & 63;
    int wid  = t >> 6;
    if (lane == 0) red[wid] = acc;
    __syncthreads();
    if (t == 0) {
        double s = 0.0;
#pragma unroll
        for (int i = 0; i < BLOCK / 64; ++i) s += red[i];
        atomicAdd(ws_sum, s);
    }
}

__global__ void adl_finalize(const double* __restrict__ ws,
                             float* __restrict__ out, double invB) {
    out[0] = (float)(ws[0] * invB);
}

extern "C" void kernel_launch(void* const* d_in, const int* in_sizes, int n_in,
                              void* d_out, int out_size, void* d_ws, size_t ws_size,
                              hipStream_t stream) {
    const float* logits = (const float*)d_in[0];
    const int*   hard   = (const int*)d_in[1];
    const float* soft   = (const float*)d_in[2];
    const float* conf   = (const float*)d_in[3];

    int B = in_sizes[1];   // batch size (hard_labels count)

    double* ws = (double*)d_ws;
    hipMemsetAsync(ws, 0, sizeof(double), stream);

    int grid = (B + SPB - 1) / SPB;   // 8192 blocks for B = 8388608
    adl_main<<<grid, BLOCK, 0, stream>>>((const float4*)logits, hard,
                                         (const float4*)soft, conf,
                                         ws, B);
    adl_finalize<<<1, 1, 0, stream>>>(ws, (float*)d_out, 1.0 / (double)B);
}

// Round 2
// 269.163 us; speedup vs baseline: 1.0505x; 1.0505x over previous
//
#include <hip/hip_runtime.h>

static constexpr int BLOCK = 256;
static constexpr int SPT   = 4;              // samples per thread per tile
static constexpr int SPB   = BLOCK * SPT;    // 1024 samples per tile
static constexpr int F4PT  = SPB * 3 / 4;    // 768 float4 per array per tile
static constexpr int GRID0 = 2048;           // 8192 tiles / 2048 = 4 tiles/block exactly

__device__ __forceinline__ float sample_contrib(float l0, float l1, float l2,
                                                float t0, float t1, float t2,
                                                float c, int lab) {
    float temp;
    if (c > 0.9f)      temp = 1.5f;
    else if (c > 0.6f) temp = 2.0f;
    else               temp = fminf(2.5f + (0.6f - c) * 2.0f, 3.0f);
    float invT = 1.0f / temp;

    float a0 = l0 * invT, a1 = l1 * invT, a2 = l2 * invT;
    float m  = fmaxf(a0, fmaxf(a1, a2));
    float s  = __expf(a0 - m) + __expf(a1 - m) + __expf(a2 - m);
    float lse = __logf(s) + m;

    float tlogt = t0 * __logf(t0) + t1 * __logf(t1) + t2 * __logf(t2);
    float ta    = t0 * a0 + t1 * a1 + t2 * a2;
    float kl    = tlogt - ta + lse;

    float m2 = fmaxf(l0, fmaxf(l1, l2));
    float s2 = __expf(l0 - m2) + __expf(l1 - m2) + __expf(l2 - m2);
    float lse2 = __logf(s2) + m2;
    float ll = (lab == 0) ? l0 : ((lab == 1) ? l1 : l2);
    float ce = lse2 - ll;

    return 0.5f * kl + 0.5f * ce;
}

// Pipelined double-buffer streaming kernel.
//  - Coalesced: 16 B/lane unit-stride global_load_lds (8 lines/instr, vs 48 at
//    the 96 B/lane register version).
//  - Never drains vmcnt in the loop: counted s_waitcnt vmcnt(14) + raw s_barrier
//    keeps the NEXT tile's 14 loads in flight across the barrier (T3/T4 pattern;
//    __syncthreads would emit vmcnt(0) and re-serialize -- that was round 1's bug).
__global__ __launch_bounds__(BLOCK) void adl_main(
    const float4* __restrict__ l4,
    const int*    __restrict__ hard,
    const float4* __restrict__ s4,
    const float*  __restrict__ conf,
    double*       __restrict__ ws_sum,
    int nt, long long B)
{
    __shared__ float ldsL[2][SPB * 3];   // 2 x 12288 B
    __shared__ float ldsS[2][SPB * 3];   // 2 x 12288 B  (total 48 KiB -> 3 blk/CU)

    const int t   = threadIdx.x;
    const int bid = blockIdx.x;
    const int G   = gridDim.x;
    float part = 0.0f;

    // 14 vmem ops per STAGE: 6 global_load_lds + 4 conf + 4 hard.
#define STAGE(BUF, TILE, CF, LB)                                                   \
    do {                                                                           \
        const float4* gl_ = l4 + (size_t)(TILE) * F4PT;                            \
        const float4* gs_ = s4 + (size_t)(TILE) * F4PT;                            \
        _Pragma("unroll")                                                          \
        for (int k = 0; k < 3; ++k)                                                \
            __builtin_amdgcn_global_load_lds(                                      \
                (const __attribute__((address_space(1))) void*)(gl_ + k * BLOCK + t), \
                (__attribute__((address_space(3))) void*)(&ldsL[BUF][(k * BLOCK + t) * 4]), \
                16, 0, 0);                                                         \
        _Pragma("unroll")                                                          \
        for (int k = 0; k < 3; ++k)                                                \
            __builtin_amdgcn_global_load_lds(                                      \
                (const __attribute__((address_space(1))) void*)(gs_ + k * BLOCK + t), \
                (__attribute__((address_space(3))) void*)(&ldsS[BUF][(k * BLOCK + t) * 4]), \
                16, 0, 0);                                                         \
        long long sb_ = (long long)(TILE) * SPB;                                   \
        _Pragma("unroll")                                                          \
        for (int j = 0; j < SPT; ++j) {                                            \
            CF[j] = conf[sb_ + j * BLOCK + t];                                     \
            LB[j] = hard[sb_ + j * BLOCK + t];                                     \
        }                                                                          \
    } while (0)

    // Own-wave data guaranteed in LDS BEFORE the barrier (producer-side wait);
    // "memory" clobber stops the compiler moving LDS reads above it.
#define WAIT14() asm volatile("s_waitcnt vmcnt(14)" ::: "memory")
#define WAIT0()  asm volatile("s_waitcnt vmcnt(0)"  ::: "memory")
#define BAR()                                    \
    do {                                         \
        __builtin_amdgcn_s_barrier();            \
        __builtin_amdgcn_sched_barrier(0);       \
    } while (0)

#define COMPUTE(BUF, CF, LB)                                                       \
    do {                                                                           \
        _Pragma("unroll")                                                          \
        for (int j = 0; j < SPT; ++j) {                                            \
            int s_ = j * BLOCK + t;  /* word addr 3t+c: gcd(3,32)=1 -> 2-way, free */ \
            part += sample_contrib(ldsL[BUF][3 * s_], ldsL[BUF][3 * s_ + 1],       \
                                   ldsL[BUF][3 * s_ + 2],                          \
                                   ldsS[BUF][3 * s_], ldsS[BUF][3 * s_ + 1],       \
                                   ldsS[BUF][3 * s_ + 2], CF[j], LB[j]);           \
        }                                                                          \
    } while (0)

    // tiles for this block: bid, bid+G, bid+2G, ...  (uniform within block)
    int nb = (bid < nt) ? ((nt - 1 - bid) / G + 1) : 0;

    float cfA[SPT], cfB[SPT];
    int   lbA[SPT], lbB[SPT];

    if (nb > 0) {
        STAGE(0, bid, cfA, lbA);
        int i = 0;
        while (true) {
            // ---- phase A: compute buf0 (tile i), prefetch into buf1 (tile i+1)
            {
                bool hn = (i + 1 < nb);
                if (hn) { STAGE(1, bid + (i + 1) * G, cfB, lbB); WAIT14(); }
                else    { WAIT0(); }
                BAR();
                COMPUTE(0, cfA, lbA);
                BAR();
            }
            if (++i >= nb) break;
            // ---- phase B: compute buf1 (tile i), prefetch into buf0 (tile i+1)
            {
                bool hn = (i + 1 < nb);
                if (hn) { STAGE(0, bid + (i + 1) * G, cfA, lbA); WAIT14(); }
                else    { WAIT0(); }
                BAR();
                COMPUTE(1, cfB, lbB);
                BAR();
            }
            if (++i >= nb) break;
        }
    }

    // remainder samples (B not a multiple of SPB; not taken for B = 8388608)
    long long done = (long long)nt * SPB;
    if (done < B) {
        const float* lf = (const float*)l4;
        const float* sf = (const float*)s4;
        for (long long s = done + (long long)bid * BLOCK + t; s < B;
             s += (long long)G * BLOCK)
            part += sample_contrib(lf[3 * s], lf[3 * s + 1], lf[3 * s + 2],
                                   sf[3 * s], sf[3 * s + 1], sf[3 * s + 2],
                                   conf[s], hard[s]);
    }

#undef STAGE
#undef WAIT14
#undef WAIT0
#undef BAR
#undef COMPUTE

    // block reduction -> one double atomic
    double acc = (double)part;
#pragma unroll
    for (int off = 32; off > 0; off >>= 1)
        acc += __shfl_down(acc, off, 64);

    __shared__ double red[BLOCK / 64];
    int lane = t & 63;
    int wid  = t >> 6;
    if (lane == 0) red[wid] = acc;
    __syncthreads();
    if (t == 0) {
        double s = 0.0;
#pragma unroll
        for (int i = 0; i < BLOCK / 64; ++i) s += red[i];
        atomicAdd(ws_sum, s);
    }
}

__global__ void adl_finalize(const double* __restrict__ ws,
                             float* __restrict__ out, double invB) {
    out[0] = (float)(ws[0] * invB);
}

extern "C" void kernel_launch(void* const* d_in, const int* in_sizes, int n_in,
                              void* d_out, int out_size, void* d_ws, size_t ws_size,
                              hipStream_t stream) {
    const float* logits = (const float*)d_in[0];
    const int*   hard   = (const int*)d_in[1];
    const float* soft   = (const float*)d_in[2];
    const float* conf   = (const float*)d_in[3];

    long long B = in_sizes[1];      // batch size
    int nt = (int)(B / SPB);        // 8192 full tiles for B = 8388608

    double* ws = (double*)d_ws;
    hipMemsetAsync(ws, 0, sizeof(double), stream);

    int grid = GRID0;
    if (nt < grid) grid = (nt > 0) ? nt : 1;   // nt=8192 -> 2048 blocks, 4 tiles each

    adl_main<<<grid, BLOCK, 0, stream>>>((const float4*)logits, hard,
                                         (const float4*)soft, conf,
                                         ws, nt, B);
    adl_finalize<<<1, 1, 0, stream>>>(ws, (float*)d_out, 1.0 / (double)B);
}